// Round 6
// baseline (1411.878 us; speedup 1.0000x reference)
//
#include <hip/hip_runtime.h>
#include <math.h>

#define Bv 64
#define Jv 20000
#define NJT 625   // 20000/32
#define NBT 2     // 64/32

// Block = 32 j x 32 b; thread = 1 j x 4 b (register-blocked on b: every LDS
// read of a weight row feeds 4x FMAs). Per-j state (pre1, gate bias, LN1
// closed-form stats) computed once into LDS, shared by all 32 b's.
// __launch_bounds__(256,2): cap 2 waves/EU -> up to 256 VGPR, NO SPILL.
__global__ __launch_bounds__(256, 2) void pe_fused(
    const float* __restrict__ x, const int* __restrict__ mask,
    const int* __restrict__ atse_idx, const float* __restrict__ fe,
    const float* __restrict__ ae,
    const float* __restrict__ hW1, const float* __restrict__ hb1,
    const float* __restrict__ hl1g, const float* __restrict__ hl1b,
    const float* __restrict__ hW2, const float* __restrict__ hb2,
    const float* __restrict__ hl2g, const float* __restrict__ hl2b,
    const float* __restrict__ gW1, const float* __restrict__ gb1,
    const float* __restrict__ gW2, const float* __restrict__ gb2,
    float* __restrict__ acc_g, float* __restrict__ se_g) {
  __shared__ __align__(16) float s_pre1[32 * 68];
  __shared__ __align__(16) float s_ex[32 * 4];
  __shared__ __align__(16) float s_gb[32 * 28];
  __shared__ __align__(16) float s_w0[64], s_l1g[64], s_l1b[64], s_hb1[64];
  __shared__ __align__(16) float s_b2[32], s_l2g[32], s_l2b[32];
  __shared__ __align__(16) float s_gb1[24];
  __shared__ __align__(16) float s_gW2[96];
  __shared__ float s_gb2[4], s_scal[2];
  // Overlay (phase-disjoint):
  //  phase A (pre):    fe[32*33]=1056 | hW1f[2048] | ae[32*20]=640 | gW1b[384]
  //  phase B (compute): W2[2048] | gW1h[768]   (staged after pre-phase)
  //  phase C (reduce):  s_e[256*5]=1280 | s_h[256*36]=9216
  __shared__ __align__(16) float s_ovl[10496];

  int tid = threadIdx.x;
  int btile = blockIdx.x;   // 0..1
  int jtile = blockIdx.y;   // 0..624

  float* s_fe   = s_ovl;            // [32][33]
  float* s_hW1f = s_ovl + 1056;     // [32][64] rows 1..32 of hW1
  float* s_ae   = s_ovl + 3104;     // [32][20]
  float* s_gW1b = s_ovl + 3744;     // [16][24]
  float* s_W2   = s_ovl;            // [64][32]  (phase B)
  float* s_gW1h = s_ovl + 2048;     // [32][24]  (phase B)
  float* s_e    = s_ovl;            // [256][5]  (phase C)
  float* s_h    = s_ovl + 1280;     // [256][36] (phase C)

  // ---------------- stage phase A ----------------
  for (int i = tid; i < 1024; i += 256)
    s_fe[(i >> 5) * 33 + (i & 31)] = fe[(size_t)jtile * 1024 + i];
  for (int i = tid; i < 2048; i += 256) s_hW1f[i] = hW1[64 + i];
  for (int i = tid; i < 384; i += 256) s_gW1b[i] = gW1[768 + i];
  if (tid < 96) s_gW2[tid] = gW2[tid];
  if (tid < 64) {
    s_w0[tid] = hW1[tid]; s_l1g[tid] = hl1g[tid];
    s_l1b[tid] = hl1b[tid]; s_hb1[tid] = hb1[tid];
  }
  if (tid < 32) { s_b2[tid] = hb2[tid]; s_l2g[tid] = hl2g[tid]; s_l2b[tid] = hl2b[tid]; }
  if (tid < 24) s_gb1[tid] = gb1[tid];
  if (tid < 4) s_gb2[tid] = gb2[tid];
  if (tid < 32) {
    int ai = atse_idx[jtile * 32 + tid];
    const float4* av = (const float4*)(ae + (size_t)ai * 16);
#pragma unroll
    for (int q = 0; q < 4; ++q) *(float4*)(s_ae + tid * 20 + q * 4) = av[q];
  }
  __syncthreads();

  // ---------------- per-j pre-compute (8 threads per j) ----------------
  {
    int jp = tid >> 3, ks = tid & 7;
    float a8[8];
#pragma unroll
    for (int kk = 0; kk < 8; ++kk) a8[kk] = s_hb1[ks * 8 + kk];
#pragma unroll 4
    for (int d = 0; d < 32; ++d) {
      float Fd = s_fe[jp * 33 + d];
      const float* wr = s_hW1f + d * 64 + ks * 8;
#pragma unroll
      for (int kk = 0; kk < 8; ++kk) a8[kk] = fmaf(Fd, wr[kk], a8[kk]);
    }
#pragma unroll
    for (int kk = 0; kk < 8; ++kk) s_pre1[jp * 68 + ks * 8 + kk] = a8[kk];

    int c0 = ks * 3;
    float g3[3] = {s_gb1[c0], s_gb1[c0 + 1], s_gb1[c0 + 2]};
#pragma unroll 4
    for (int a = 0; a < 16; ++a) {
      float Av = s_ae[jp * 20 + a];
      const float* gr = s_gW1b + a * 24 + c0;
      g3[0] = fmaf(Av, gr[0], g3[0]);
      g3[1] = fmaf(Av, gr[1], g3[1]);
      g3[2] = fmaf(Av, gr[2], g3[2]);
    }
    s_gb[jp * 28 + c0] = g3[0];
    s_gb[jp * 28 + c0 + 1] = g3[1];
    s_gb[jp * 28 + c0 + 2] = g3[2];
  }
  __syncthreads();

  // ---------------- LN1 stats (tid<33) + stage phase B (all threads) --------
  if (tid < 32) {
    float sp = 0.f, qp = 0.f, dwp = 0.f;
#pragma unroll 8
    for (int k = 0; k < 64; ++k) {
      float p = s_pre1[tid * 68 + k];
      float w = s_w0[k];
      sp += p;
      qp = fmaf(p, p, qp);
      dwp = fmaf(p, w, dwp);
    }
    ((float4*)s_ex)[tid] = make_float4(sp, qp, dwp, 0.f);
  } else if (tid == 32) {
    float sw = 0.f, qw = 0.f;
    for (int k = 0; k < 64; ++k) {
      float w = s_w0[k];
      sw += w;
      qw = fmaf(w, w, qw);
    }
    s_scal[0] = sw;
    s_scal[1] = qw;
  }
  for (int i = tid; i < 2048; i += 256) s_W2[i] = hW2[i];
  for (int i = tid; i < 768; i += 256) s_gW1h[i] = gW1[i];
  __syncthreads();

  // ---------------- compute: thread = 1 j x 4 b ----------------
  int jl = tid & 31, bg = tid >> 5;
  int b0 = btile * 32 + bg * 4;
  size_t xoff = (size_t)jtile * 32 + jl;
  float xv[4];
  int mv[4];
#pragma unroll
  for (int bb = 0; bb < 4; ++bb) {
    xv[bb] = x[(size_t)(b0 + bb) * Jv + xoff];
    mv[bb] = mask[(size_t)(b0 + bb) * Jv + xoff];
  }

  float4 ex = ((const float4*)s_ex)[jl];
  float Sw0 = s_scal[0], Qw0 = s_scal[1];
  float rs1[4], nm1[4];
#pragma unroll
  for (int bb = 0; bb < 4; ++bb) {
    float mu1 = fmaf(xv[bb], Sw0, ex.x) * 0.015625f;
    float Et2 = fmaf(xv[bb] * xv[bb], Qw0, fmaf(2.0f * xv[bb], ex.z, ex.y)) * 0.015625f;
    rs1[bb] = rsqrtf(fmaxf(Et2 - mu1 * mu1, 0.f) + 1e-5f);
    nm1[bb] = -mu1 * rs1[bb];
  }

  float h2[4][32];
#pragma unroll
  for (int q = 0; q < 8; ++q) {
    float4 bb4 = ((const float4*)s_b2)[q];
#pragma unroll
    for (int bb = 0; bb < 4; ++bb) {
      h2[bb][4 * q] = bb4.x; h2[bb][4 * q + 1] = bb4.y;
      h2[bb][4 * q + 2] = bb4.z; h2[bb][4 * q + 3] = bb4.w;
    }
  }
  const float4* pr4 = (const float4*)(s_pre1 + jl * 68);
#pragma unroll 4
  for (int k4 = 0; k4 < 16; ++k4) {
    float4 p = pr4[k4];
    float4 w04 = ((const float4*)s_w0)[k4];
    float4 g4 = ((const float4*)s_l1g)[k4];
    float4 b4 = ((const float4*)s_l1b)[k4];
    float pu[4] = {p.x, p.y, p.z, p.w};
    float wu[4] = {w04.x, w04.y, w04.z, w04.w};
    float gu[4] = {g4.x, g4.y, g4.z, g4.w};
    float bu[4] = {b4.x, b4.y, b4.z, b4.w};
#pragma unroll
    for (int u = 0; u < 4; ++u) {
      float a[4];
#pragma unroll
      for (int bb = 0; bb < 4; ++bb)
        a[bb] = fmaxf(fmaf(fmaf(fmaf(xv[bb], wu[u], pu[u]), rs1[bb], nm1[bb]),
                           gu[u], bu[u]), 0.f);
      const float4* row = (const float4*)(s_W2 + (k4 * 4 + u) * 32);
#pragma unroll
      for (int q = 0; q < 8; ++q) {
        float4 w = row[q];
#pragma unroll
        for (int bb = 0; bb < 4; ++bb) {
          h2[bb][4 * q]     = fmaf(a[bb], w.x, h2[bb][4 * q]);
          h2[bb][4 * q + 1] = fmaf(a[bb], w.y, h2[bb][4 * q + 1]);
          h2[bb][4 * q + 2] = fmaf(a[bb], w.z, h2[bb][4 * q + 2]);
          h2[bb][4 * q + 3] = fmaf(a[bb], w.w, h2[bb][4 * q + 3]);
        }
      }
    }
  }

  // ---------------- LN2 + relu (per bb) ----------------
#pragma unroll
  for (int bb = 0; bb < 4; ++bb) {
    float s = 0.f;
#pragma unroll
    for (int d = 0; d < 32; ++d) s += h2[bb][d];
    float mu2 = s * 0.03125f;
    float vv = 0.f;
#pragma unroll
    for (int d = 0; d < 32; ++d) { float dd = h2[bb][d] - mu2; vv = fmaf(dd, dd, vv); }
    float rs2 = rsqrtf(vv * 0.03125f + 1e-5f);
#pragma unroll
    for (int d = 0; d < 32; ++d)
      h2[bb][d] = fmaxf(fmaf((h2[bb][d] - mu2) * rs2, s_l2g[d], s_l2b[d]), 0.f);
  }

  // ---------------- gate: 2 passes x 2 b's (shared row reads) ----------------
  float e[4][4];
#pragma unroll
  for (int gp = 0; gp < 2; ++gp) {
    int ba = gp * 2, bbx = gp * 2 + 1;
    float g1a[24], g1b[24];
    const float4* gbv = (const float4*)(s_gb + jl * 28);
#pragma unroll
    for (int c4 = 0; c4 < 6; ++c4) {
      float4 v = gbv[c4];
      g1a[4 * c4] = v.x; g1a[4 * c4 + 1] = v.y;
      g1a[4 * c4 + 2] = v.z; g1a[4 * c4 + 3] = v.w;
      g1b[4 * c4] = v.x; g1b[4 * c4 + 1] = v.y;
      g1b[4 * c4 + 2] = v.z; g1b[4 * c4 + 3] = v.w;
    }
#pragma unroll 8
    for (int i = 0; i < 32; ++i) {
      float ha = h2[ba][i], hb = h2[bbx][i];
      const float4* row = (const float4*)(s_gW1h + i * 24);
#pragma unroll
      for (int c4 = 0; c4 < 6; ++c4) {
        float4 w = row[c4];
        g1a[4 * c4]     = fmaf(ha, w.x, g1a[4 * c4]);
        g1a[4 * c4 + 1] = fmaf(ha, w.y, g1a[4 * c4 + 1]);
        g1a[4 * c4 + 2] = fmaf(ha, w.z, g1a[4 * c4 + 2]);
        g1a[4 * c4 + 3] = fmaf(ha, w.w, g1a[4 * c4 + 3]);
        g1b[4 * c4]     = fmaf(hb, w.x, g1b[4 * c4]);
        g1b[4 * c4 + 1] = fmaf(hb, w.y, g1b[4 * c4 + 1]);
        g1b[4 * c4 + 2] = fmaf(hb, w.z, g1b[4 * c4 + 2]);
        g1b[4 * c4 + 3] = fmaf(hb, w.w, g1b[4 * c4 + 3]);
      }
    }
    float ra0 = s_gb2[0], ra1 = s_gb2[1], ra2 = s_gb2[2], ra3 = s_gb2[3];
    float rb0 = ra0, rb1 = ra1, rb2 = ra2, rb3 = ra3;
#pragma unroll
    for (int c = 0; c < 24; ++c) {
      float va = fmaxf(g1a[c], 0.f), vb = fmaxf(g1b[c], 0.f);
      float4 w = ((const float4*)s_gW2)[c];
      ra0 = fmaf(va, w.x, ra0); rb0 = fmaf(vb, w.x, rb0);
      ra1 = fmaf(va, w.y, ra1); rb1 = fmaf(vb, w.y, rb1);
      ra2 = fmaf(va, w.z, ra2); rb2 = fmaf(vb, w.z, rb2);
      ra3 = fmaf(va, w.w, ra3); rb3 = fmaf(vb, w.w, rb3);
    }
    ra0 = fminf(fmaxf(ra0, -10.f), 10.f); ra1 = fminf(fmaxf(ra1, -10.f), 10.f);
    ra2 = fminf(fmaxf(ra2, -10.f), 10.f); ra3 = fminf(fmaxf(ra3, -10.f), 10.f);
    rb0 = fminf(fmaxf(rb0, -10.f), 10.f); rb1 = fminf(fmaxf(rb1, -10.f), 10.f);
    rb2 = fminf(fmaxf(rb2, -10.f), 10.f); rb3 = fminf(fmaxf(rb3, -10.f), 10.f);
    bool aa = mv[ba] != 0, ab = mv[bbx] != 0;
    e[ba][0] = aa ? __expf(ra0 - 10.f) : 0.f;
    e[ba][1] = aa ? __expf(ra1 - 10.f) : 0.f;
    e[ba][2] = aa ? __expf(ra2 - 10.f) : 0.f;
    e[ba][3] = aa ? __expf(ra3 - 10.f) : 0.f;
    e[bbx][0] = ab ? __expf(rb0 - 10.f) : 0.f;
    e[bbx][1] = ab ? __expf(rb1 - 10.f) : 0.f;
    e[bbx][2] = ab ? __expf(rb2 - 10.f) : 0.f;
    e[bbx][3] = ab ? __expf(rb3 - 10.f) : 0.f;
  }

  // ---------------- reduce: 4 passes (one per bb), full-d staging -----------
#pragma unroll
  for (int bb = 0; bb < 4; ++bb) {
    __syncthreads();   // protect previous pass reads / phase-B weights
    s_e[tid * 5 + 0] = e[bb][0];
    s_e[tid * 5 + 1] = e[bb][1];
    s_e[tid * 5 + 2] = e[bb][2];
    s_e[tid * 5 + 3] = e[bb][3];
#pragma unroll
    for (int q = 0; q < 8; ++q)
      *(float4*)(s_h + tid * 36 + q * 4) =
          make_float4(h2[bb][4 * q], h2[bb][4 * q + 1],
                      h2[bb][4 * q + 2], h2[bb][4 * q + 3]);
    __syncthreads();
    int rbg = tid >> 5, rw = (tid >> 3) & 3, rd4 = tid & 7;
    float a0 = 0.f, a1 = 0.f, a2 = 0.f, a3 = 0.f, ses = 0.f;
#pragma unroll 8
    for (int jj = 0; jj < 32; ++jj) {
      int slot = rbg * 32 + jj;
      float evv = s_e[slot * 5 + rw];
      float4 hv = *(const float4*)(s_h + slot * 36 + rd4 * 4);
      a0 = fmaf(evv, hv.x, a0);
      a1 = fmaf(evv, hv.y, a1);
      a2 = fmaf(evv, hv.z, a2);
      a3 = fmaf(evv, hv.w, a3);
      ses += evv;
    }
    int bt = btile * 32 + rbg * 4 + bb;
    float* dst = acc_g + (size_t)bt * 128 + rw * 32 + rd4 * 4;
    atomicAdd(dst + 0, a0);
    atomicAdd(dst + 1, a1);
    atomicAdd(dst + 2, a2);
    atomicAdd(dst + 3, a3);
    if (rd4 == 0) atomicAdd(&se_g[bt * 4 + rw], ses);
  }
}

// ---------------- per-b tail: normalize, c-layer, encoder MLP ----------------
__global__ __launch_bounds__(64) void pe_tail(
    const float* __restrict__ acc_g, const float* __restrict__ se_g,
    const float* __restrict__ cW, const float* __restrict__ cb,
    const float* __restrict__ clng, const float* __restrict__ clnb,
    const float* __restrict__ eW1, const float* __restrict__ eb1,
    const float* __restrict__ eW2, const float* __restrict__ eb2,
    float* __restrict__ out) {
  int b = blockIdx.x;
  int lane = threadIdx.x;  // 64 threads = 1 wave
  __shared__ float s_hs[128], s_comb[32], s_e1[128];

  float se0 = se_g[b * 4 + 0];
  bool empty = !(se0 > 0.0f);
  float inv[4];
#pragma unroll
  for (int w = 0; w < 4; ++w) {
    float sw = se_g[b * 4 + w];
    inv[w] = empty ? 0.0f : 1.0f / sw;
  }
  s_hs[lane] = acc_g[b * 128 + lane] * inv[lane >> 5];
  s_hs[lane + 64] = acc_g[b * 128 + lane + 64] * inv[(lane + 64) >> 5];
  __syncthreads();

  if (lane < 32) {
    float cp = cb[lane];
#pragma unroll 8
    for (int i = 0; i < 128; ++i) cp = fmaf(s_hs[i], cW[i * 32 + lane], cp);
    float ssum = cp;
#pragma unroll
    for (int off = 16; off > 0; off >>= 1) ssum += __shfl_xor(ssum, off, 32);
    float mu = ssum * (1.0f / 32.0f);
    float dd = cp - mu;
    float sq = dd * dd;
#pragma unroll
    for (int off = 16; off > 0; off >>= 1) sq += __shfl_xor(sq, off, 32);
    float rs = rsqrtf(sq * (1.0f / 32.0f) + 1e-5f);
    float comb = fmaxf(fmaf(dd * rs, clng[lane], clnb[lane]), 0.0f);
    if (empty) comb = 0.0f;
    s_comb[lane] = comb;
  }
  __syncthreads();

  float v0 = eb1[lane], v1 = eb1[lane + 64];
#pragma unroll
  for (int i = 0; i < 32; ++i) {
    float c = s_comb[i];
    v0 = fmaf(c, eW1[i * 128 + lane], v0);
    v1 = fmaf(c, eW1[i * 128 + lane + 64], v1);
  }
  float ssum = v0 + v1;
#pragma unroll
  for (int off = 32; off > 0; off >>= 1) ssum += __shfl_xor(ssum, off, 64);
  float mu = ssum * (1.0f / 128.0f);
  float d0 = v0 - mu, d1 = v1 - mu;
  float sq = fmaf(d0, d0, d1 * d1);
#pragma unroll
  for (int off = 32; off > 0; off >>= 1) sq += __shfl_xor(sq, off, 64);
  float rs = rsqrtf(sq * (1.0f / 128.0f) + 1e-5f);
  s_e1[lane] = fmaxf(d0 * rs, 0.0f);
  s_e1[lane + 64] = fmaxf(d1 * rs, 0.0f);
  __syncthreads();

  float v = eb2[lane];
#pragma unroll 8
  for (int i = 0; i < 128; ++i) v = fmaf(s_e1[i], eW2[i * 64 + lane], v);
  ssum = v;
#pragma unroll
  for (int off = 32; off > 0; off >>= 1) ssum += __shfl_xor(ssum, off, 64);
  mu = ssum * (1.0f / 64.0f);
  float dv = v - mu;
  sq = dv * dv;
#pragma unroll
  for (int off = 32; off > 0; off >>= 1) sq += __shfl_xor(sq, off, 64);
  rs = rsqrtf(sq * (1.0f / 64.0f) + 1e-5f);
  float o = fmaxf(dv * rs, 0.0f);
  if (lane < 32)
    out[b * 32 + lane] = o;                       // mu
  else
    out[Bv * 32 + b * 32 + (lane - 32)] = o;      // logvar
}

extern "C" void kernel_launch(void* const* d_in, const int* in_sizes, int n_in,
                              void* d_out, int out_size, void* d_ws, size_t ws_size,
                              hipStream_t stream) {
  const float* x    = (const float*)d_in[0];
  const int* mask   = (const int*)d_in[1];
  const int* atse   = (const int*)d_in[2];
  const float* fe   = (const float*)d_in[3];
  const float* ae   = (const float*)d_in[4];
  const float* hW1  = (const float*)d_in[5];
  const float* hb1  = (const float*)d_in[6];
  const float* hl1g = (const float*)d_in[7];
  const float* hl1b = (const float*)d_in[8];
  const float* hW2  = (const float*)d_in[9];
  const float* hb2  = (const float*)d_in[10];
  const float* hl2g = (const float*)d_in[11];
  const float* hl2b = (const float*)d_in[12];
  const float* gW1  = (const float*)d_in[13];
  const float* gb1  = (const float*)d_in[14];
  const float* gW2  = (const float*)d_in[15];
  const float* gb2  = (const float*)d_in[16];
  const float* cW   = (const float*)d_in[17];
  const float* cb   = (const float*)d_in[18];
  const float* clng = (const float*)d_in[19];
  const float* clnb = (const float*)d_in[20];
  const float* eW1  = (const float*)d_in[21];
  const float* eb1  = (const float*)d_in[22];
  const float* eW2  = (const float*)d_in[23];
  const float* eb2  = (const float*)d_in[24];
  float* out = (float*)d_out;

  float* ws = (float*)d_ws;
  float* accg = ws;                 // B*128 floats
  float* seg  = accg + Bv * 128;    // B*4 floats

  hipMemsetAsync(accg, 0, (Bv * 128 + Bv * 4) * sizeof(float), stream);

  pe_fused<<<dim3(NBT, NJT), dim3(256), 0, stream>>>(
      x, mask, atse, fe, ae, hW1, hb1, hl1g, hl1b, hW2, hb2, hl2g, hl2b,
      gW1, gb1, gW2, gb2, accg, seg);
  pe_tail<<<dim3(Bv), dim3(64), 0, stream>>>(
      accg, seg, cW, cb, clng, clnb, eW1, eb1, eW2, eb2, out);
}

// Round 7
// 292.555 us; speedup vs baseline: 4.8260x; 4.8260x over previous
//
#include <hip/hip_runtime.h>
#include <math.h>

#define Bv 64
#define Jv 20000
#define NJT 625   // j tiles (32 j each)
#define NBT 8     // b tiles (8 b each)

typedef __attribute__((ext_vector_type(8))) short short8;
typedef __attribute__((ext_vector_type(4))) float f32x4;

__device__ __forceinline__ unsigned short f2bf(float f) {
  unsigned int u = __float_as_uint(f);
  u += 0x7FFFu + ((u >> 16) & 1u);
  return (unsigned short)(u >> 16);
}
__device__ __forceinline__ float bflo(unsigned int u) { return __uint_as_float(u << 16); }
__device__ __forceinline__ float bfhi(unsigned int u) { return __uint_as_float(u & 0xFFFF0000u); }

// Block = 32 j x 8 b = 256 pairs (pair id m = j*8 + b), 256 threads.
// pre1 and h@W2 via MFMA (B-operands in registers); gate + reduce on VALU.
__global__ __launch_bounds__(256) void pe_fused(
    const float* __restrict__ x, const int* __restrict__ mask,
    const int* __restrict__ atse_idx, const float* __restrict__ fe,
    const float* __restrict__ ae,
    const float* __restrict__ hW1, const float* __restrict__ hb1,
    const float* __restrict__ hl1g, const float* __restrict__ hl1b,
    const float* __restrict__ hW2, const float* __restrict__ hb2,
    const float* __restrict__ hl2g, const float* __restrict__ hl2b,
    const float* __restrict__ gW1, const float* __restrict__ gb1,
    const float* __restrict__ gW2, const float* __restrict__ gb2,
    float* __restrict__ acc_g, float* __restrict__ se_g) {
  __shared__ __align__(16) float s_pg[32 * 68];     // pre1, then pre1*gamma
  __shared__ __align__(16) float s_ex[32 * 4];      // sp, qp, dwp per j
  __shared__ __align__(16) float s_gb[32 * 28];     // gate bias per j
  __shared__ __align__(16) float s_pair[256 * 4];   // xr, rs1, nm1 per pair
  __shared__ __align__(16) float s_e[256 * 4];      // softmax numerators
  __shared__ __align__(16) float s_ae[32 * 20];
  __shared__ __align__(16) float s_gW1b[16 * 24];
  __shared__ __align__(16) float s_w0[64], s_w0g[64], s_l1g[64], s_l1b[64];
  __shared__ __align__(16) float s_b2[32], s_l2g[32], s_l2b[32];
  __shared__ __align__(16) float s_gb1[24], s_gW2[96];
  __shared__ float s_gb2[4], s_scal[2];
  __shared__ __align__(16) unsigned short s_gW1bf[32 * 24];  // bf16 gate weights
  // overlay: phase<=3: W2 fp32 [64*32]=8192B ; phase>=4: s_h bf16 [256][40]=20480B
  __shared__ __align__(16) unsigned short s_ovl[256 * 40];

  int tid = threadIdx.x;
  int btile = blockIdx.x;   // 0..7
  int jtile = blockIdx.y;   // 0..624
  int J0 = jtile * 32;
  int lane = tid & 63, wv = tid >> 6;
  int li = lane & 15, quad = lane >> 4;

  float* ovlf = (float*)s_ovl;            // W2 fp32 staging (phases 0-3)
  unsigned short* s_h = s_ovl;            // ho bf16, stride 40 (phases 4-6)

  // ---------------- P0: stage globals ----------------
  for (int i = tid; i < 2048; i += 256) ovlf[i] = hW2[i];
  for (int i = tid; i < 768; i += 256) s_gW1bf[i] = f2bf(gW1[i]);
  for (int i = tid; i < 384; i += 256) s_gW1b[i] = gW1[768 + i];
  if (tid < 96) s_gW2[tid] = gW2[tid];
  if (tid < 64) { s_w0[tid] = hW1[tid]; s_l1g[tid] = hl1g[tid]; s_l1b[tid] = hl1b[tid]; }
  if (tid < 32) { s_b2[tid] = hb2[tid]; s_l2g[tid] = hl2g[tid]; s_l2b[tid] = hl2b[tid]; }
  if (tid < 24) s_gb1[tid] = gb1[tid];
  if (tid < 4) s_gb2[tid] = gb2[tid];
  if (tid < 32) {
    int ai = atse_idx[J0 + tid];
    const float4* av = (const float4*)(ae + (size_t)ai * 16);
#pragma unroll
    for (int q = 0; q < 4; ++q) *(float4*)(s_ae + tid * 20 + q * 4) = av[q];
  }
  __syncthreads();

  // ---------------- P1: pre1 via MFMA (wave wv owns cols wv*16..+15) -------
  {
    // B-frag: hW1 rows 1..32 (d), cols wv*16+li
    short8 bH;
#pragma unroll
    for (int i = 0; i < 8; ++i)
      bH[i] = (short)f2bf(hW1[(1 + quad * 8 + i) * 64 + wv * 16 + li]);
    float hb = hb1[wv * 16 + li];
    f32x4 cP[2];
#pragma unroll
    for (int mt = 0; mt < 2; ++mt) {
      cP[mt][0] = hb; cP[mt][1] = hb; cP[mt][2] = hb; cP[mt][3] = hb;
      const float* fp = fe + (size_t)(J0 + mt * 16 + li) * 32 + quad * 8;
      float4 f0 = *(const float4*)fp;
      float4 f1 = *(const float4*)(fp + 4);
      short8 aF;
      aF[0] = (short)f2bf(f0.x); aF[1] = (short)f2bf(f0.y);
      aF[2] = (short)f2bf(f0.z); aF[3] = (short)f2bf(f0.w);
      aF[4] = (short)f2bf(f1.x); aF[5] = (short)f2bf(f1.y);
      aF[6] = (short)f2bf(f1.z); aF[7] = (short)f2bf(f1.w);
      cP[mt] = __builtin_amdgcn_mfma_f32_16x16x32_bf16(aF, bH, cP[mt], 0, 0, 0);
#pragma unroll
      for (int r = 0; r < 4; ++r)
        s_pg[(mt * 16 + quad * 4 + r) * 68 + wv * 16 + li] = cP[mt][r];
    }
  }
  // gate bias per j (8 threads per j, 3 c's per thread)
  {
    int jp = tid >> 3, ks = tid & 7;
    int c0 = ks * 3;
    float g3[3] = {s_gb1[c0], s_gb1[c0 + 1], s_gb1[c0 + 2]};
#pragma unroll 4
    for (int a = 0; a < 16; ++a) {
      float Av = s_ae[jp * 20 + a];
      const float* gr = s_gW1b + a * 24 + c0;
      g3[0] = fmaf(Av, gr[0], g3[0]);
      g3[1] = fmaf(Av, gr[1], g3[1]);
      g3[2] = fmaf(Av, gr[2], g3[2]);
    }
    s_gb[jp * 28 + c0] = g3[0];
    s_gb[jp * 28 + c0 + 1] = g3[1];
    s_gb[jp * 28 + c0 + 2] = g3[2];
  }
  __syncthreads();

  // ---------------- P2: LN1 closed-form stats (raw pre1) + w0*gamma --------
  if (tid < 32) {
    float sp = 0.f, qp = 0.f, dwp = 0.f;
#pragma unroll 8
    for (int k = 0; k < 64; ++k) {
      float p = s_pg[tid * 68 + k];
      float w = s_w0[k];
      sp += p;
      qp = fmaf(p, p, qp);
      dwp = fmaf(p, w, dwp);
    }
    ((float4*)s_ex)[tid] = make_float4(sp, qp, dwp, 0.f);
  } else if (tid == 32) {
    float sw = 0.f, qw = 0.f;
    for (int k = 0; k < 64; ++k) {
      float w = s_w0[k];
      sw += w;
      qw = fmaf(w, w, qw);
    }
    s_scal[0] = sw;
    s_scal[1] = qw;
  } else if (tid >= 64 && tid < 128) {
    s_w0g[tid - 64] = s_w0[tid - 64] * s_l1g[tid - 64];
  }
  __syncthreads();

  // ---------------- P3: fold pg *= gamma; build W2 B-frags; pair scalars ---
  {
    int jp = tid >> 3, ks = tid & 7;
    float* pp = s_pg + jp * 68 + ks * 8;
    float4 a0 = *(float4*)pp, a1 = *(float4*)(pp + 4);
    float4 g0 = *(float4*)(s_l1g + ks * 8), g1 = *(float4*)(s_l1g + ks * 8 + 4);
    a0.x *= g0.x; a0.y *= g0.y; a0.z *= g0.z; a0.w *= g0.w;
    a1.x *= g1.x; a1.y *= g1.y; a1.z *= g1.z; a1.w *= g1.w;
    *(float4*)pp = a0;
    *(float4*)(pp + 4) = a1;
  }
  short8 bW2[2][2];
#pragma unroll
  for (int kt = 0; kt < 2; ++kt)
#pragma unroll
    for (int nt = 0; nt < 2; ++nt)
#pragma unroll
      for (int i = 0; i < 8; ++i)
        bW2[kt][nt][i] =
            (short)f2bf(ovlf[(kt * 32 + quad * 8 + i) * 32 + nt * 16 + li]);
  int mv;
  {
    int j = tid >> 3, b = tid & 7;
    size_t off = (size_t)(btile * 8 + b) * Jv + J0 + j;
    float xv = x[off];
    mv = mask[off];
    float4 ex = ((const float4*)s_ex)[j];
    float mu1 = fmaf(xv, s_scal[0], ex.x) * 0.015625f;
    float Et2 = fmaf(xv * xv, s_scal[1], fmaf(2.0f * xv, ex.z, ex.y)) * 0.015625f;
    float rs1 = rsqrtf(fmaxf(Et2 - mu1 * mu1, 0.f) + 1e-5f);
    *(float4*)(s_pair + tid * 4) = make_float4(xv * rs1, rs1, -mu1 * rs1, 0.f);
  }
  __syncthreads();

  // ---------------- P4: a-frags in regs -> MFMA h2 -> LN2 -> s_h bf16 ------
  {
    f32x4 cd[4][2];
    float b2a = s_b2[li], b2b = s_b2[16 + li];
#pragma unroll
    for (int t = 0; t < 4; ++t) {
      cd[t][0][0] = b2a; cd[t][0][1] = b2a; cd[t][0][2] = b2a; cd[t][0][3] = b2a;
      cd[t][1][0] = b2b; cd[t][1][1] = b2b; cd[t][1][2] = b2b; cd[t][1][3] = b2b;
    }
#pragma unroll
    for (int kt = 0; kt < 2; ++kt) {
      int base = kt * 32 + quad * 8;
      float4 wg0 = *(const float4*)(s_w0g + base);
      float4 wg1 = *(const float4*)(s_w0g + base + 4);
      float4 gg0 = *(const float4*)(s_l1g + base);
      float4 gg1 = *(const float4*)(s_l1g + base + 4);
      float4 bb0 = *(const float4*)(s_l1b + base);
      float4 bb1 = *(const float4*)(s_l1b + base + 4);
      float wg[8] = {wg0.x, wg0.y, wg0.z, wg0.w, wg1.x, wg1.y, wg1.z, wg1.w};
      float gg[8] = {gg0.x, gg0.y, gg0.z, gg0.w, gg1.x, gg1.y, gg1.z, gg1.w};
      float bb[8] = {bb0.x, bb0.y, bb0.z, bb0.w, bb1.x, bb1.y, bb1.z, bb1.w};
#pragma unroll
      for (int t = 0; t < 4; ++t) {
        int mrow = wv * 64 + t * 16 + li;
        float4 pr = *(const float4*)(s_pair + mrow * 4);
        const float* pgp = s_pg + (mrow >> 3) * 68 + base;
        float4 p0 = *(const float4*)pgp;
        float4 p1 = *(const float4*)(pgp + 4);
        float pv[8] = {p0.x, p0.y, p0.z, p0.w, p1.x, p1.y, p1.z, p1.w};
        short8 af;
#pragma unroll
        for (int i = 0; i < 8; ++i) {
          float a = fmaf(pr.x, wg[i], fmaf(pr.y, pv[i], fmaf(pr.z, gg[i], bb[i])));
          af[i] = (short)f2bf(fmaxf(a, 0.f));
        }
        cd[t][0] = __builtin_amdgcn_mfma_f32_16x16x32_bf16(af, bW2[kt][0], cd[t][0], 0, 0, 0);
        cd[t][1] = __builtin_amdgcn_mfma_f32_16x16x32_bf16(af, bW2[kt][1], cd[t][1], 0, 0, 0);
      }
    }
    // LN2 + relu epilogue, write ho bf16 (row stride 40 ushorts)
    float g0 = s_l2g[li], be0 = s_l2b[li];
    float g1v = s_l2g[16 + li], be1 = s_l2b[16 + li];
#pragma unroll
    for (int t = 0; t < 4; ++t) {
      float sum[4], sq[4];
#pragma unroll
      for (int r = 0; r < 4; ++r) {
        float a = cd[t][0][r], b = cd[t][1][r];
        sum[r] = a + b;
        sq[r] = fmaf(a, a, b * b);
      }
#pragma unroll
      for (int off = 1; off < 16; off <<= 1) {
#pragma unroll
        for (int r = 0; r < 4; ++r) {
          sum[r] += __shfl_xor(sum[r], off);
          sq[r] += __shfl_xor(sq[r], off);
        }
      }
#pragma unroll
      for (int r = 0; r < 4; ++r) {
        float mu = sum[r] * 0.03125f;
        float var = sq[r] * 0.03125f - mu * mu;
        float rs2 = rsqrtf(fmaxf(var, 0.f) + 1e-5f);
        int m = wv * 64 + t * 16 + quad * 4 + r;
        float h0 = fmaxf(fmaf((cd[t][0][r] - mu) * rs2, g0, be0), 0.f);
        float h1 = fmaxf(fmaf((cd[t][1][r] - mu) * rs2, g1v, be1), 0.f);
        s_h[m * 40 + li] = f2bf(h0);
        s_h[m * 40 + 16 + li] = f2bf(h1);
      }
    }
  }
  __syncthreads();

  // ---------------- P5: gate (VALU, bf16 weights) ----------------
  {
    float ho[32];
#pragma unroll
    for (int q = 0; q < 4; ++q) {
      uint4 u = *(const uint4*)(s_h + tid * 40 + q * 8);
      ho[q * 8 + 0] = bflo(u.x); ho[q * 8 + 1] = bfhi(u.x);
      ho[q * 8 + 2] = bflo(u.y); ho[q * 8 + 3] = bfhi(u.y);
      ho[q * 8 + 4] = bflo(u.z); ho[q * 8 + 5] = bfhi(u.z);
      ho[q * 8 + 6] = bflo(u.w); ho[q * 8 + 7] = bfhi(u.w);
    }
    int j = tid >> 3;
    float g1[24];
    const float4* gbv = (const float4*)(s_gb + j * 28);
#pragma unroll
    for (int c4 = 0; c4 < 6; ++c4) {
      float4 v = gbv[c4];
      g1[4 * c4] = v.x; g1[4 * c4 + 1] = v.y;
      g1[4 * c4 + 2] = v.z; g1[4 * c4 + 3] = v.w;
    }
#pragma unroll 4
    for (int i = 0; i < 32; ++i) {
      float hv = ho[i];
      const unsigned short* row = s_gW1bf + i * 24;
      uint4 ua = *(const uint4*)row;
      uint4 ub = *(const uint4*)(row + 8);
      uint4 uc = *(const uint4*)(row + 16);
      unsigned int us[12] = {ua.x, ua.y, ua.z, ua.w, ub.x, ub.y,
                             ub.z, ub.w, uc.x, uc.y, uc.z, uc.w};
#pragma unroll
      for (int cp = 0; cp < 12; ++cp) {
        g1[2 * cp] = fmaf(hv, bflo(us[cp]), g1[2 * cp]);
        g1[2 * cp + 1] = fmaf(hv, bfhi(us[cp]), g1[2 * cp + 1]);
      }
    }
    float r0 = s_gb2[0], r1 = s_gb2[1], r2 = s_gb2[2], r3 = s_gb2[3];
#pragma unroll
    for (int c = 0; c < 24; ++c) {
      float gv = fmaxf(g1[c], 0.f);
      float4 w = ((const float4*)s_gW2)[c];
      r0 = fmaf(gv, w.x, r0);
      r1 = fmaf(gv, w.y, r1);
      r2 = fmaf(gv, w.z, r2);
      r3 = fmaf(gv, w.w, r3);
    }
    r0 = fminf(fmaxf(r0, -10.f), 10.f);
    r1 = fminf(fmaxf(r1, -10.f), 10.f);
    r2 = fminf(fmaxf(r2, -10.f), 10.f);
    r3 = fminf(fmaxf(r3, -10.f), 10.f);
    bool act = (mv != 0);
    float e0 = act ? __expf(r0 - 10.f) : 0.f;
    float e1 = act ? __expf(r1 - 10.f) : 0.f;
    float e2 = act ? __expf(r2 - 10.f) : 0.f;
    float e3 = act ? __expf(r3 - 10.f) : 0.f;
    *(float4*)(s_e + tid * 4) = make_float4(e0, e1, e2, e3);
  }
  __syncthreads();

  // ---------------- P6: reduce + atomics ----------------
  {
    int b = tid >> 5, w = (tid >> 3) & 3, dsl = tid & 7;
    float a0 = 0.f, a1 = 0.f, a2 = 0.f, a3 = 0.f, ses = 0.f;
#pragma unroll 8
    for (int j = 0; j < 32; ++j) {
      int m = j * 8 + b;
      float ev = s_e[m * 4 + w];
      uint2 u = *(const uint2*)(s_h + m * 40 + dsl * 4);
      a0 = fmaf(ev, bflo(u.x), a0);
      a1 = fmaf(ev, bfhi(u.x), a1);
      a2 = fmaf(ev, bflo(u.y), a2);
      a3 = fmaf(ev, bfhi(u.y), a3);
      ses += ev;
    }
    float* dst = acc_g + (size_t)(btile * 8 + b) * 128 + w * 32 + dsl * 4;
    atomicAdd(dst + 0, a0);
    atomicAdd(dst + 1, a1);
    atomicAdd(dst + 2, a2);
    atomicAdd(dst + 3, a3);
    if (dsl == 0) atomicAdd(&se_g[(btile * 8 + b) * 4 + w], ses);
  }
}

// ---------------- per-b tail: normalize, c-layer, encoder MLP ----------------
__global__ __launch_bounds__(64) void pe_tail(
    const float* __restrict__ acc_g, const float* __restrict__ se_g,
    const float* __restrict__ cW, const float* __restrict__ cb,
    const float* __restrict__ clng, const float* __restrict__ clnb,
    const float* __restrict__ eW1, const float* __restrict__ eb1,
    const float* __restrict__ eW2, const float* __restrict__ eb2,
    float* __restrict__ out) {
  int b = blockIdx.x;
  int lane = threadIdx.x;  // 64 threads = 1 wave
  __shared__ float s_hs[128], s_comb[32], s_e1[128];

  float se0 = se_g[b * 4 + 0];
  bool empty = !(se0 > 0.0f);
  float inv[4];
#pragma unroll
  for (int w = 0; w < 4; ++w) {
    float sw = se_g[b * 4 + w];
    inv[w] = empty ? 0.0f : 1.0f / sw;
  }
  s_hs[lane] = acc_g[b * 128 + lane] * inv[lane >> 5];
  s_hs[lane + 64] = acc_g[b * 128 + lane + 64] * inv[(lane + 64) >> 5];
  __syncthreads();

  if (lane < 32) {
    float cp = cb[lane];
#pragma unroll 8
    for (int i = 0; i < 128; ++i) cp = fmaf(s_hs[i], cW[i * 32 + lane], cp);
    float ssum = cp;
#pragma unroll
    for (int off = 16; off > 0; off >>= 1) ssum += __shfl_xor(ssum, off, 32);
    float mu = ssum * (1.0f / 32.0f);
    float dd = cp - mu;
    float sq = dd * dd;
#pragma unroll
    for (int off = 16; off > 0; off >>= 1) sq += __shfl_xor(sq, off, 32);
    float rs = rsqrtf(sq * (1.0f / 32.0f) + 1e-5f);
    float comb = fmaxf(fmaf(dd * rs, clng[lane], clnb[lane]), 0.0f);
    if (empty) comb = 0.0f;
    s_comb[lane] = comb;
  }
  __syncthreads();

  float v0 = eb1[lane], v1 = eb1[lane + 64];
#pragma unroll
  for (int i = 0; i < 32; ++i) {
    float c = s_comb[i];
    v0 = fmaf(c, eW1[i * 128 + lane], v0);
    v1 = fmaf(c, eW1[i * 128 + lane + 64], v1);
  }
  float ssum = v0 + v1;
#pragma unroll
  for (int off = 32; off > 0; off >>= 1) ssum += __shfl_xor(ssum, off, 64);
  float mu = ssum * (1.0f / 128.0f);
  float d0 = v0 - mu, d1 = v1 - mu;
  float sq = fmaf(d0, d0, d1 * d1);
#pragma unroll
  for (int off = 32; off > 0; off >>= 1) sq += __shfl_xor(sq, off, 64);
  float rs = rsqrtf(sq * (1.0f / 128.0f) + 1e-5f);
  s_e1[lane] = fmaxf(d0 * rs, 0.0f);
  s_e1[lane + 64] = fmaxf(d1 * rs, 0.0f);
  __syncthreads();

  float v = eb2[lane];
#pragma unroll 8
  for (int i = 0; i < 128; ++i) v = fmaf(s_e1[i], eW2[i * 64 + lane], v);
  ssum = v;
#pragma unroll
  for (int off = 32; off > 0; off >>= 1) ssum += __shfl_xor(ssum, off, 64);
  mu = ssum * (1.0f / 64.0f);
  float dv = v - mu;
  sq = dv * dv;
#pragma unroll
  for (int off = 32; off > 0; off >>= 1) sq += __shfl_xor(sq, off, 64);
  rs = rsqrtf(sq * (1.0f / 64.0f) + 1e-5f);
  float o = fmaxf(dv * rs, 0.0f);
  if (lane < 32)
    out[b * 32 + lane] = o;                       // mu
  else
    out[Bv * 32 + b * 32 + (lane - 32)] = o;      // logvar
}

extern "C" void kernel_launch(void* const* d_in, const int* in_sizes, int n_in,
                              void* d_out, int out_size, void* d_ws, size_t ws_size,
                              hipStream_t stream) {
  const float* x    = (const float*)d_in[0];
  const int* mask   = (const int*)d_in[1];
  const int* atse   = (const int*)d_in[2];
  const float* fe   = (const float*)d_in[3];
  const float* ae   = (const float*)d_in[4];
  const float* hW1  = (const float*)d_in[5];
  const float* hb1  = (const float*)d_in[6];
  const float* hl1g = (const float*)d_in[7];
  const float* hl1b = (const float*)d_in[8];
  const float* hW2  = (const float*)d_in[9];
  const float* hb2  = (const float*)d_in[10];
  const float* hl2g = (const float*)d_in[11];
  const float* hl2b = (const float*)d_in[12];
  const float* gW1  = (const float*)d_in[13];
  const float* gb1  = (const float*)d_in[14];
  const float* gW2  = (const float*)d_in[15];
  const float* gb2  = (const float*)d_in[16];
  const float* cW   = (const float*)d_in[17];
  const float* cb   = (const float*)d_in[18];
  const float* clng = (const float*)d_in[19];
  const float* clnb = (const float*)d_in[20];
  const float* eW1  = (const float*)d_in[21];
  const float* eb1  = (const float*)d_in[22];
  const float* eW2  = (const float*)d_in[23];
  const float* eb2  = (const float*)d_in[24];
  float* out = (float*)d_out;

  float* ws = (float*)d_ws;
  float* accg = ws;                 // B*128 floats
  float* seg  = accg + Bv * 128;    // B*4 floats

  hipMemsetAsync(accg, 0, (Bv * 128 + Bv * 4) * sizeof(float), stream);

  pe_fused<<<dim3(NBT, NJT), dim3(256), 0, stream>>>(
      x, mask, atse, fe, ae, hW1, hb1, hl1g, hl1b, hW2, hb2, hl2g, hl2b,
      gW1, gb1, gW2, gb2, accg, seg);
  pe_tail<<<dim3(Bv), dim3(64), 0, stream>>>(
      accg, seg, cW, cb, clng, clnb, eW1, eb1, eW2, eb2, out);
}

// Round 8
// 269.386 us; speedup vs baseline: 5.2411x; 1.0860x over previous
//
#include <hip/hip_runtime.h>
#include <math.h>

#define Bv 64
#define Jv 20000
#define NJT 625   // j tiles (32 j each)
#define NBT 8     // b tiles (8 b each)

typedef __attribute__((ext_vector_type(8))) short short8;
typedef __attribute__((ext_vector_type(4))) float f32x4;

union U8 { short8 s; unsigned int u[4]; };

__device__ __forceinline__ unsigned short f2bf(float f) {
  unsigned int u = __float_as_uint(f);
  u += 0x7FFFu + ((u >> 16) & 1u);
  return (unsigned short)(u >> 16);
}
__device__ __forceinline__ float bflo(unsigned int u) { return __uint_as_float(u << 16); }
__device__ __forceinline__ float bfhi(unsigned int u) { return __uint_as_float(u & 0xFFFF0000u); }

// Block = 32 j x 8 b = 256 pairs (pair id m = j*8 + b), 256 threads.
// pre1, h@W2, and gate-layer1 via MFMA; gate-layer2 via quad-butterfly (fp32).
// s_h stride 34 ushorts (17 words, odd -> <=2-way banks), b32 accesses only.
__global__ __launch_bounds__(256) void pe_fused(
    const float* __restrict__ x, const int* __restrict__ mask,
    const int* __restrict__ atse_idx, const float* __restrict__ fe,
    const float* __restrict__ ae,
    const float* __restrict__ hW1, const float* __restrict__ hb1,
    const float* __restrict__ hl1g, const float* __restrict__ hl1b,
    const float* __restrict__ hW2, const float* __restrict__ hb2,
    const float* __restrict__ hl2g, const float* __restrict__ hl2b,
    const float* __restrict__ gW1, const float* __restrict__ gb1,
    const float* __restrict__ gW2, const float* __restrict__ gb2,
    float* __restrict__ acc_g, float* __restrict__ se_g) {
  __shared__ __align__(16) float s_pg[32 * 68];      // pre1, then pre1*gamma
  __shared__ __align__(16) float s_ex[32 * 4];       // sp, qp, dwp per j
  __shared__ __align__(16) float s_gb[32 * 28 + 16]; // gate bias per j (+pad)
  __shared__ __align__(16) float s_pair[256 * 4];    // xr, rs1, nm1 per pair
  __shared__ __align__(16) float s_e[256 * 4];       // softmax numerators
  __shared__ __align__(16) float s_ae[32 * 20];
  __shared__ __align__(16) float s_gW1b[16 * 24];
  __shared__ __align__(16) float s_w0[64], s_w0g[64], s_l1g[64], s_l1b[64];
  __shared__ __align__(16) float s_b2[32], s_l2g[32], s_l2b[32];
  __shared__ __align__(16) float s_gb1[24], s_gW2[96];
  __shared__ float s_gb2[4], s_scal[2];
  __shared__ int s_mk[256];
  __shared__ __align__(16) unsigned short s_gW1bf[32 * 24];  // bf16 gate weights
  // overlay: P0-P3: W2 fp32 staging (8192 B); P4+: s_h bf16 [256][34]
  __shared__ __align__(16) unsigned short s_ovl[256 * 34];

  int tid = threadIdx.x;
  int btile = blockIdx.x;   // 0..7
  int jtile = blockIdx.y;   // 0..624
  int J0 = jtile * 32;
  int lane = tid & 63, wv = tid >> 6;
  int li = lane & 15, quad = lane >> 4;

  float* ovlf = (float*)s_ovl;            // W2 fp32 staging (phases 0-3)
  unsigned short* s_h = s_ovl;            // ho bf16, stride 34 (phases 4-6)

  // ---------------- P0: stage globals ----------------
  for (int i = tid; i < 2048; i += 256) ovlf[i] = hW2[i];
  for (int i = tid; i < 768; i += 256) s_gW1bf[i] = f2bf(gW1[i]);
  for (int i = tid; i < 384; i += 256) s_gW1b[i] = gW1[768 + i];
  if (tid < 96) s_gW2[tid] = gW2[tid];
  if (tid < 64) { s_w0[tid] = hW1[tid]; s_l1g[tid] = hl1g[tid]; s_l1b[tid] = hl1b[tid]; }
  if (tid < 32) { s_b2[tid] = hb2[tid]; s_l2g[tid] = hl2g[tid]; s_l2b[tid] = hl2b[tid]; }
  if (tid < 24) s_gb1[tid] = gb1[tid];
  if (tid < 4) s_gb2[tid] = gb2[tid];
  if (tid >= 128 && tid < 144) s_gb[32 * 28 + (tid - 128)] = 0.f;  // pad
  if (tid >= 144 && tid < 272 && tid < 256) { /* no-op keep uniform */ }
  if (tid < 128) s_gb[(tid >> 2) * 28 + 24 + (tid & 3)] = 0.f;     // cols 24..27
  if (tid < 32) {
    int ai = atse_idx[J0 + tid];
    const float4* av = (const float4*)(ae + (size_t)ai * 16);
#pragma unroll
    for (int q = 0; q < 4; ++q) *(float4*)(s_ae + tid * 20 + q * 4) = av[q];
  }
  __syncthreads();

  // ---------------- P1: pre1 via MFMA (wave wv owns cols wv*16..+15) -------
  {
    short8 bH;
#pragma unroll
    for (int i = 0; i < 8; ++i)
      bH[i] = (short)f2bf(hW1[(1 + quad * 8 + i) * 64 + wv * 16 + li]);
    float hb = hb1[wv * 16 + li];
    f32x4 cP[2];
#pragma unroll
    for (int mt = 0; mt < 2; ++mt) {
      cP[mt][0] = hb; cP[mt][1] = hb; cP[mt][2] = hb; cP[mt][3] = hb;
      const float* fp = fe + (size_t)(J0 + mt * 16 + li) * 32 + quad * 8;
      float4 f0 = *(const float4*)fp;
      float4 f1 = *(const float4*)(fp + 4);
      short8 aF;
      aF[0] = (short)f2bf(f0.x); aF[1] = (short)f2bf(f0.y);
      aF[2] = (short)f2bf(f0.z); aF[3] = (short)f2bf(f0.w);
      aF[4] = (short)f2bf(f1.x); aF[5] = (short)f2bf(f1.y);
      aF[6] = (short)f2bf(f1.z); aF[7] = (short)f2bf(f1.w);
      cP[mt] = __builtin_amdgcn_mfma_f32_16x16x32_bf16(aF, bH, cP[mt], 0, 0, 0);
#pragma unroll
      for (int r = 0; r < 4; ++r)
        s_pg[(mt * 16 + quad * 4 + r) * 68 + wv * 16 + li] = cP[mt][r];
    }
  }
  // gate bias per j (8 threads per j, 3 c's per thread)
  {
    int jp = tid >> 3, ks = tid & 7;
    int c0 = ks * 3;
    float g3[3] = {s_gb1[c0], s_gb1[c0 + 1], s_gb1[c0 + 2]};
#pragma unroll 4
    for (int a = 0; a < 16; ++a) {
      float Av = s_ae[jp * 20 + a];
      const float* gr = s_gW1b + a * 24 + c0;
      g3[0] = fmaf(Av, gr[0], g3[0]);
      g3[1] = fmaf(Av, gr[1], g3[1]);
      g3[2] = fmaf(Av, gr[2], g3[2]);
    }
    s_gb[jp * 28 + c0] = g3[0];
    s_gb[jp * 28 + c0 + 1] = g3[1];
    s_gb[jp * 28 + c0 + 2] = g3[2];
  }
  __syncthreads();

  // ---------------- P2: LN1 closed-form stats + w0*gamma ----------------
  if (tid < 32) {
    float sp = 0.f, qp = 0.f, dwp = 0.f;
#pragma unroll 8
    for (int k = 0; k < 64; ++k) {
      float p = s_pg[tid * 68 + k];
      float w = s_w0[k];
      sp += p;
      qp = fmaf(p, p, qp);
      dwp = fmaf(p, w, dwp);
    }
    ((float4*)s_ex)[tid] = make_float4(sp, qp, dwp, 0.f);
  } else if (tid == 32) {
    float sw = 0.f, qw = 0.f;
    for (int k = 0; k < 64; ++k) {
      float w = s_w0[k];
      sw += w;
      qw = fmaf(w, w, qw);
    }
    s_scal[0] = sw;
    s_scal[1] = qw;
  } else if (tid >= 64 && tid < 128) {
    s_w0g[tid - 64] = s_w0[tid - 64] * s_l1g[tid - 64];
  }
  __syncthreads();

  // ---------------- P3: fold pg *= gamma; W2 B-frags; pair scalars ---------
  {
    int jp = tid >> 3, ks = tid & 7;
    float* pp = s_pg + jp * 68 + ks * 8;
    float4 a0 = *(float4*)pp, a1 = *(float4*)(pp + 4);
    float4 g0 = *(float4*)(s_l1g + ks * 8), g1 = *(float4*)(s_l1g + ks * 8 + 4);
    a0.x *= g0.x; a0.y *= g0.y; a0.z *= g0.z; a0.w *= g0.w;
    a1.x *= g1.x; a1.y *= g1.y; a1.z *= g1.z; a1.w *= g1.w;
    *(float4*)pp = a0;
    *(float4*)(pp + 4) = a1;
  }
  short8 bW2[2][2];
#pragma unroll
  for (int kt = 0; kt < 2; ++kt)
#pragma unroll
    for (int nt = 0; nt < 2; ++nt)
#pragma unroll
      for (int i = 0; i < 8; ++i)
        bW2[kt][nt][i] =
            (short)f2bf(ovlf[(kt * 32 + quad * 8 + i) * 32 + nt * 16 + li]);
  {
    int j = tid >> 3, b = tid & 7;
    size_t off = (size_t)(btile * 8 + b) * Jv + J0 + j;
    float xv = x[off];
    s_mk[tid] = mask[off];
    float4 ex = ((const float4*)s_ex)[j];
    float mu1 = fmaf(xv, s_scal[0], ex.x) * 0.015625f;
    float Et2 = fmaf(xv * xv, s_scal[1], fmaf(2.0f * xv, ex.z, ex.y)) * 0.015625f;
    float rs1 = rsqrtf(fmaxf(Et2 - mu1 * mu1, 0.f) + 1e-5f);
    *(float4*)(s_pair + tid * 4) = make_float4(xv * rs1, rs1, -mu1 * rs1, 0.f);
  }
  __syncthreads();

  // ---------------- P4: a-frags in regs -> MFMA h2 -> LN2 -> s_h bf16 ------
  {
    f32x4 cd[4][2];
    float b2a = s_b2[li], b2b = s_b2[16 + li];
#pragma unroll
    for (int t = 0; t < 4; ++t) {
      cd[t][0][0] = b2a; cd[t][0][1] = b2a; cd[t][0][2] = b2a; cd[t][0][3] = b2a;
      cd[t][1][0] = b2b; cd[t][1][1] = b2b; cd[t][1][2] = b2b; cd[t][1][3] = b2b;
    }
#pragma unroll
    for (int kt = 0; kt < 2; ++kt) {
      int base = kt * 32 + quad * 8;
      float4 wg0 = *(const float4*)(s_w0g + base);
      float4 wg1 = *(const float4*)(s_w0g + base + 4);
      float4 gg0 = *(const float4*)(s_l1g + base);
      float4 gg1 = *(const float4*)(s_l1g + base + 4);
      float4 bb0 = *(const float4*)(s_l1b + base);
      float4 bb1 = *(const float4*)(s_l1b + base + 4);
      float wg[8] = {wg0.x, wg0.y, wg0.z, wg0.w, wg1.x, wg1.y, wg1.z, wg1.w};
      float gg[8] = {gg0.x, gg0.y, gg0.z, gg0.w, gg1.x, gg1.y, gg1.z, gg1.w};
      float bb[8] = {bb0.x, bb0.y, bb0.z, bb0.w, bb1.x, bb1.y, bb1.z, bb1.w};
#pragma unroll
      for (int t = 0; t < 4; ++t) {
        int mrow = wv * 64 + t * 16 + li;
        float4 pr = *(const float4*)(s_pair + mrow * 4);
        const float* pgp = s_pg + (mrow >> 3) * 68 + base;
        float4 p0 = *(const float4*)pgp;
        float4 p1 = *(const float4*)(pgp + 4);
        float pv[8] = {p0.x, p0.y, p0.z, p0.w, p1.x, p1.y, p1.z, p1.w};
        short8 af;
#pragma unroll
        for (int i = 0; i < 8; ++i) {
          float a = fmaf(pr.x, wg[i], fmaf(pr.y, pv[i], fmaf(pr.z, gg[i], bb[i])));
          af[i] = (short)f2bf(fmaxf(a, 0.f));
        }
        cd[t][0] = __builtin_amdgcn_mfma_f32_16x16x32_bf16(af, bW2[kt][0], cd[t][0], 0, 0, 0);
        cd[t][1] = __builtin_amdgcn_mfma_f32_16x16x32_bf16(af, bW2[kt][1], cd[t][1], 0, 0, 0);
      }
    }
    // LN2 + relu epilogue, write ho bf16 (row stride 34 ushorts)
    float g0 = s_l2g[li], be0 = s_l2b[li];
    float g1v = s_l2g[16 + li], be1 = s_l2b[16 + li];
#pragma unroll
    for (int t = 0; t < 4; ++t) {
      float sum[4], sq[4];
#pragma unroll
      for (int r = 0; r < 4; ++r) {
        float a = cd[t][0][r], b = cd[t][1][r];
        sum[r] = a + b;
        sq[r] = fmaf(a, a, b * b);
      }
#pragma unroll
      for (int off = 1; off < 16; off <<= 1) {
#pragma unroll
        for (int r = 0; r < 4; ++r) {
          sum[r] += __shfl_xor(sum[r], off);
          sq[r] += __shfl_xor(sq[r], off);
        }
      }
#pragma unroll
      for (int r = 0; r < 4; ++r) {
        float mu = sum[r] * 0.03125f;
        float var = sq[r] * 0.03125f - mu * mu;
        float rs2 = rsqrtf(fmaxf(var, 0.f) + 1e-5f);
        int m = wv * 64 + t * 16 + quad * 4 + r;
        float h0 = fmaxf(fmaf((cd[t][0][r] - mu) * rs2, g0, be0), 0.f);
        float h1 = fmaxf(fmaf((cd[t][1][r] - mu) * rs2, g1v, be1), 0.f);
        s_h[m * 34 + li] = f2bf(h0);
        s_h[m * 34 + 16 + li] = f2bf(h1);
      }
    }
  }
  // (no barrier: P5 consumes only own-wave s_h rows; DS ops in-order per wave)

  // ---------------- P5: gate via transposed MFMA + quad-butterfly ----------
  {
    // A-frags: gW1^T (rows c, k = ho dim). Tile mt=1 rows c>=24 are zero.
    short8 aG0, aG1;
#pragma unroll
    for (int i = 0; i < 8; ++i) {
      int k = quad * 8 + i;
      aG0[i] = (short)s_gW1bf[k * 24 + li];
      aG1[i] = (li < 8) ? (short)s_gW1bf[k * 24 + 16 + li] : (short)0;
    }
    float4 gw4[2][4];
#pragma unroll
    for (int mt = 0; mt < 2; ++mt)
#pragma unroll
      for (int r = 0; r < 4; ++r) {
        int c = mt * 16 + quad * 4 + r;
        gw4[mt][r] = (c < 24) ? ((const float4*)s_gW2)[c]
                              : make_float4(0.f, 0.f, 0.f, 0.f);
      }
#pragma unroll
    for (int nt = 0; nt < 4; ++nt) {
      int m = wv * 64 + nt * 16 + li;
      // B-frag: ho row m, k = quad*8+i (4x b32, stride-17-word banks)
      U8 bu;
      const unsigned short* hp = s_h + m * 34 + quad * 8;
      bu.u[0] = *(const unsigned int*)(hp + 0);
      bu.u[1] = *(const unsigned int*)(hp + 2);
      bu.u[2] = *(const unsigned int*)(hp + 4);
      bu.u[3] = *(const unsigned int*)(hp + 6);
      int j = m >> 3;
      f32x4 c0, c1;
#pragma unroll
      for (int r = 0; r < 4; ++r) {
        c0[r] = s_gb[j * 28 + quad * 4 + r];
        c1[r] = s_gb[j * 28 + 16 + quad * 4 + r];
      }
      c0 = __builtin_amdgcn_mfma_f32_16x16x32_bf16(aG0, bu.s, c0, 0, 0, 0);
      c1 = __builtin_amdgcn_mfma_f32_16x16x32_bf16(aG1, bu.s, c1, 0, 0, 0);
      // layer 2: r[w] = sum_c relu(g1[c]) * gW2[c][w], partial per quad
      float r0 = s_gb2[0], r1 = s_gb2[1], r2 = s_gb2[2], r3 = s_gb2[3];
#pragma unroll
      for (int r = 0; r < 4; ++r) {
        float v0 = fmaxf(c0[r], 0.f);
        float v1 = fmaxf(c1[r], 0.f);
        float4 ga = gw4[0][r], gb = gw4[1][r];
        r0 = fmaf(v0, ga.x, fmaf(v1, gb.x, r0));
        r1 = fmaf(v0, ga.y, fmaf(v1, gb.y, r1));
        r2 = fmaf(v0, ga.z, fmaf(v1, gb.z, r2));
        r3 = fmaf(v0, ga.w, fmaf(v1, gb.w, r3));
      }
      // reduce over quads (lanes li, li+16, li+32, li+48)
      r0 += __shfl_xor(r0, 16); r0 += __shfl_xor(r0, 32);
      r1 += __shfl_xor(r1, 16); r1 += __shfl_xor(r1, 32);
      r2 += __shfl_xor(r2, 16); r2 += __shfl_xor(r2, 32);
      r3 += __shfl_xor(r3, 16); r3 += __shfl_xor(r3, 32);
      r0 = fminf(fmaxf(r0, -10.f), 10.f);
      r1 = fminf(fmaxf(r1, -10.f), 10.f);
      r2 = fminf(fmaxf(r2, -10.f), 10.f);
      r3 = fminf(fmaxf(r3, -10.f), 10.f);
      bool act = (s_mk[m] != 0);
      float e0 = act ? __expf(r0 - 10.f) : 0.f;
      float e1 = act ? __expf(r1 - 10.f) : 0.f;
      float e2 = act ? __expf(r2 - 10.f) : 0.f;
      float e3 = act ? __expf(r3 - 10.f) : 0.f;
      if (quad == 0) *(float4*)(s_e + m * 4) = make_float4(e0, e1, e2, e3);
    }
  }
  __syncthreads();

  // ---------------- P6: reduce + atomics ----------------
  {
    int b = tid >> 5, w = (tid >> 3) & 3, dsl = tid & 7;
    float a0 = 0.f, a1 = 0.f, a2 = 0.f, a3 = 0.f, ses = 0.f;
#pragma unroll 8
    for (int j = 0; j < 32; ++j) {
      int m = j * 8 + b;
      float ev = s_e[m * 4 + w];
      unsigned int ua = *(const unsigned int*)(s_h + m * 34 + dsl * 4);
      unsigned int ub = *(const unsigned int*)(s_h + m * 34 + dsl * 4 + 2);
      a0 = fmaf(ev, bflo(ua), a0);
      a1 = fmaf(ev, bfhi(ua), a1);
      a2 = fmaf(ev, bflo(ub), a2);
      a3 = fmaf(ev, bfhi(ub), a3);
      ses += ev;
    }
    float* dst = acc_g + (size_t)(btile * 8 + b) * 128 + w * 32 + dsl * 4;
    atomicAdd(dst + 0, a0);
    atomicAdd(dst + 1, a1);
    atomicAdd(dst + 2, a2);
    atomicAdd(dst + 3, a3);
    if (dsl == 0) atomicAdd(&se_g[(btile * 8 + b) * 4 + w], ses);
  }
}

// ---------------- per-b tail: normalize, c-layer, encoder MLP ----------------
__global__ __launch_bounds__(64) void pe_tail(
    const float* __restrict__ acc_g, const float* __restrict__ se_g,
    const float* __restrict__ cW, const float* __restrict__ cb,
    const float* __restrict__ clng, const float* __restrict__ clnb,
    const float* __restrict__ eW1, const float* __restrict__ eb1,
    const float* __restrict__ eW2, const float* __restrict__ eb2,
    float* __restrict__ out) {
  int b = blockIdx.x;
  int lane = threadIdx.x;  // 64 threads = 1 wave
  __shared__ float s_hs[128], s_comb[32], s_e1[128];

  float se0 = se_g[b * 4 + 0];
  bool empty = !(se0 > 0.0f);
  float inv[4];
#pragma unroll
  for (int w = 0; w < 4; ++w) {
    float sw = se_g[b * 4 + w];
    inv[w] = empty ? 0.0f : 1.0f / sw;
  }
  s_hs[lane] = acc_g[b * 128 + lane] * inv[lane >> 5];
  s_hs[lane + 64] = acc_g[b * 128 + lane + 64] * inv[(lane + 64) >> 5];
  __syncthreads();

  if (lane < 32) {
    float cp = cb[lane];
#pragma unroll 8
    for (int i = 0; i < 128; ++i) cp = fmaf(s_hs[i], cW[i * 32 + lane], cp);
    float ssum = cp;
#pragma unroll
    for (int off = 16; off > 0; off >>= 1) ssum += __shfl_xor(ssum, off, 32);
    float mu = ssum * (1.0f / 32.0f);
    float dd = cp - mu;
    float sq = dd * dd;
#pragma unroll
    for (int off = 16; off > 0; off >>= 1) sq += __shfl_xor(sq, off, 32);
    float rs = rsqrtf(sq * (1.0f / 32.0f) + 1e-5f);
    float comb = fmaxf(fmaf(dd * rs, clng[lane], clnb[lane]), 0.0f);
    if (empty) comb = 0.0f;
    s_comb[lane] = comb;
  }
  __syncthreads();

  float v0 = eb1[lane], v1 = eb1[lane + 64];
#pragma unroll
  for (int i = 0; i < 32; ++i) {
    float c = s_comb[i];
    v0 = fmaf(c, eW1[i * 128 + lane], v0);
    v1 = fmaf(c, eW1[i * 128 + lane + 64], v1);
  }
  float ssum = v0 + v1;
#pragma unroll
  for (int off = 32; off > 0; off >>= 1) ssum += __shfl_xor(ssum, off, 64);
  float mu = ssum * (1.0f / 128.0f);
  float d0 = v0 - mu, d1 = v1 - mu;
  float sq = fmaf(d0, d0, d1 * d1);
#pragma unroll
  for (int off = 32; off > 0; off >>= 1) sq += __shfl_xor(sq, off, 64);
  float rs = rsqrtf(sq * (1.0f / 128.0f) + 1e-5f);
  s_e1[lane] = fmaxf(d0 * rs, 0.0f);
  s_e1[lane + 64] = fmaxf(d1 * rs, 0.0f);
  __syncthreads();

  float v = eb2[lane];
#pragma unroll 8
  for (int i = 0; i < 128; ++i) v = fmaf(s_e1[i], eW2[i * 64 + lane], v);
  ssum = v;
#pragma unroll
  for (int off = 32; off > 0; off >>= 1) ssum += __shfl_xor(ssum, off, 64);
  mu = ssum * (1.0f / 64.0f);
  float dv = v - mu;
  sq = dv * dv;
#pragma unroll
  for (int off = 32; off > 0; off >>= 1) sq += __shfl_xor(sq, off, 64);
  rs = rsqrtf(sq * (1.0f / 64.0f) + 1e-5f);
  float o = fmaxf(dv * rs, 0.0f);
  if (lane < 32)
    out[b * 32 + lane] = o;                       // mu
  else
    out[Bv * 32 + b * 32 + (lane - 32)] = o;      // logvar
}

extern "C" void kernel_launch(void* const* d_in, const int* in_sizes, int n_in,
                              void* d_out, int out_size, void* d_ws, size_t ws_size,
                              hipStream_t stream) {
  const float* x    = (const float*)d_in[0];
  const int* mask   = (const int*)d_in[1];
  const int* atse   = (const int*)d_in[2];
  const float* fe   = (const float*)d_in[3];
  const float* ae   = (const float*)d_in[4];
  const float* hW1  = (const float*)d_in[5];
  const float* hb1  = (const float*)d_in[6];
  const float* hl1g = (const float*)d_in[7];
  const float* hl1b = (const float*)d_in[8];
  const float* hW2  = (const float*)d_in[9];
  const float* hb2  = (const float*)d_in[10];
  const float* hl2g = (const float*)d_in[11];
  const float* hl2b = (const float*)d_in[12];
  const float* gW1  = (const float*)d_in[13];
  const float* gb1  = (const float*)d_in[14];
  const float* gW2  = (const float*)d_in[15];
  const float* gb2  = (const float*)d_in[16];
  const float* cW   = (const float*)d_in[17];
  const float* cb   = (const float*)d_in[18];
  const float* clng = (const float*)d_in[19];
  const float* clnb = (const float*)d_in[20];
  const float* eW1  = (const float*)d_in[21];
  const float* eb1  = (const float*)d_in[22];
  const float* eW2  = (const float*)d_in[23];
  const float* eb2  = (const float*)d_in[24];
  float* out = (float*)d_out;

  float* ws = (float*)d_ws;
  float* accg = ws;                 // B*128 floats
  float* seg  = accg + Bv * 128;    // B*4 floats

  hipMemsetAsync(accg, 0, (Bv * 128 + Bv * 4) * sizeof(float), stream);

  pe_fused<<<dim3(NBT, NJT), dim3(256), 0, stream>>>(
      x, mask, atse, fe, ae, hW1, hb1, hl1g, hl1b, hW2, hb2, hl2g, hl2b,
      gW1, gb1, gW2, gb2, accg, seg);
  pe_tail<<<dim3(Bv), dim3(64), 0, stream>>>(
      accg, seg, cW, cb, clng, clnb, eW1, eb1, eW2, eb2, out);
}